// Round 3
// baseline (861.972 us; speedup 1.0000x reference)
//
#include <hip/hip_runtime.h>

static constexpr int DIM   = 256;
static constexpr int NCODE = 8192;
static constexpr int NROWS = 16384;

typedef __bf16 bf16x8 __attribute__((ext_vector_type(8)));
typedef float  f32x4  __attribute__((ext_vector_type(4)));

// ---------------------------------------------------------------------------
// helpers
// ---------------------------------------------------------------------------
__device__ __forceinline__ void gload_lds16(const void* g, void* l) {
    __builtin_amdgcn_global_load_lds(
        (const __attribute__((address_space(1))) void*)g,
        (__attribute__((address_space(3))) void*)l, 16, 0, 0);
}

__device__ __forceinline__ void top2_insert(float& v0, int& i0, float& v1, int& i1,
                                            float s, int si) {
    if (s < v0) { v1 = v0; i1 = i0; v0 = s; i0 = si; }
    else if (s < v1) { v1 = s; i1 = si; }
}
__device__ __forceinline__ void top2_merge(float& v0, int& i0, float& v1, int& i1,
                                           float b0, int bi0, float b1, int bi1) {
    if (b0 < v0) {
        if (b1 < v0) { v0 = b0; i0 = bi0; v1 = b1; i1 = bi1; }
        else         { v1 = v0; i1 = i0;  v0 = b0; i0 = bi0; }
    } else if (b0 < v1) { v1 = b0; i1 = bi0; }
}

// ---------------------------------------------------------------------------
// P0 fused: [0,2048) cvt_x | [2048,2560) cvt_e (transpose+bf16+fp32) | [2560,2592) e2
// e2 chain is bit-identical to the round-1-validated version.
// ---------------------------------------------------------------------------
__global__ __launch_bounds__(256) void prep_kernel(
    const float* __restrict__ x, const float* __restrict__ embed,
    ushort* __restrict__ xb, ushort* __restrict__ eb16,
    float* __restrict__ ebT32, float* __restrict__ e2)
{
    __shared__ float tile[64][65];
    const int b = blockIdx.x;
    const int t = threadIdx.x;

    if (b < 2048) {                      // ---- cvt_x ----
        int i = b * 256 + t;
        const float4* xp = (const float4*)x + (size_t)i * 2;
        float4 a = xp[0], v = xp[1];
        bf16x8 o;
        o[0] = (__bf16)a.x; o[1] = (__bf16)a.y; o[2] = (__bf16)a.z; o[3] = (__bf16)a.w;
        o[4] = (__bf16)v.x; o[5] = (__bf16)v.y; o[6] = (__bf16)v.z; o[7] = (__bf16)v.w;
        ((bf16x8*)xb)[i] = o;
    } else if (b < 2560) {               // ---- cvt_e ----
        const int eb = b - 2048;
        const int c00 = (eb & 127) * 64;
        const int k0  = (eb >> 7) * 64;
        const int tc  = t & 63, tr4 = t >> 6;
        #pragma unroll
        for (int i = 0; i < 16; ++i) {
            int r = i * 4 + tr4;
            tile[r][tc] = embed[(size_t)(k0 + r) * NCODE + c00 + tc];
        }
        __syncthreads();
        const int cl = t >> 2;
        const int kq = t & 3;
        float vals[16];
        #pragma unroll
        for (int j = 0; j < 16; ++j) vals[j] = tile[kq * 16 + j][cl];
        float* d32 = ebT32 + (size_t)(c00 + cl) * DIM + k0 + kq * 16;
        #pragma unroll
        for (int j = 0; j < 4; ++j)
            *(float4*)(d32 + j * 4) = make_float4(vals[j*4], vals[j*4+1],
                                                  vals[j*4+2], vals[j*4+3]);
        bf16x8 h0, h1;
        #pragma unroll
        for (int j = 0; j < 8; ++j) { h0[j] = (__bf16)vals[j]; h1[j] = (__bf16)vals[8 + j]; }
        ushort* d16 = eb16 + (size_t)(c00 + cl) * DIM + k0 + kq * 16;
        *(bf16x8*)d16 = h0;
        *(bf16x8*)(d16 + 8) = h1;
    } else {                             // ---- e2 (exact serial chain) ----
        int j = (b - 2560) * 256 + t;
        float s = 0.f;
        for (int k = 0; k < DIM; ++k) {
            float v = embed[(size_t)k * NCODE + j];
            s = __fadd_rn(s, __fmul_rn(v, v));
        }
        e2[j] = s;
    }
}

// ---------------------------------------------------------------------------
// K1: full-K-resident bf16 MFMA + per-row top2 per 128-code chunk.
// Tile 128 rows x 128 codes x K=256. LDS 128 KB, single stage, ONE barrier,
// then a barrier-free 512-MFMA loop. XOR-swizzled LDS (linear dest +
// inverse-swizzled global source; read applies the same involution).
// 8 waves as 2x4; wave tile = 64 rows x 32 codes (4x2 frags).
// ---------------------------------------------------------------------------
__global__ __launch_bounds__(512, 1) void gemm_top2_kernel(
    const ushort* __restrict__ xb,   // [NROWS][256] bf16
    const ushort* __restrict__ eb,   // [NCODE][256] bf16 (embed^T)
    const float* __restrict__ e2,    // [NCODE]
    uint4* __restrict__ scratch)     // [NROWS][64]
{
    __shared__ ushort As[32768];     // [128 rows][256 k] bf16, swizzled
    __shared__ ushort Bs[32768];     // [128 codes][256 k] bf16, swizzled

    const int t = threadIdx.x;

    // XCD-bijective swizzle (nwg=8192, 8192%8==0): each XCD gets a contiguous
    // swz range -> one A-slab + ~2MB B-range live in its private L2.
    const int lin   = blockIdx.y * 64 + blockIdx.x;
    const int swz   = (lin & 7) * 1024 + (lin >> 3);
    const int chunk = swz & 63;          // code chunk (128 codes)
    const int rb    = swz >> 6;          // row block (128 rows)
    const int c0    = chunk * 128;
    const int r0    = rb * 128;

    // ---- stage full K once: linear LDS dest, inverse-swizzled global src ----
    const ushort* abase = xb + (size_t)r0 * DIM;
    const ushort* bbase = eb + (size_t)c0 * DIM;
    #pragma unroll
    for (int i = 0; i < 8; ++i) {
        int o   = i * 8192 + t * 16;     // byte offset in 64 KB tile
        int row = o >> 9;
        int cs  = (o & 511) ^ ((row & 7) << 4);
        gload_lds16(abase + row * DIM + (cs >> 1), &As[o >> 1]);
    }
    #pragma unroll
    for (int i = 0; i < 8; ++i) {
        int o   = i * 8192 + t * 16;
        int row = o >> 9;
        int cs  = (o & 511) ^ ((row & 7) << 4);
        gload_lds16(bbase + row * DIM + (cs >> 1), &Bs[o >> 1]);
    }
    __syncthreads();                     // drains vmcnt; tiles ready

    const int wid = t >> 6, lane = t & 63;
    const int wr  = wid >> 2, wc = wid & 3;   // 2x4 wave grid
    const int lr  = lane & 15, g = lane >> 4;

    f32x4 acc[4][2];
    #pragma unroll
    for (int a = 0; a < 4; ++a)
        #pragma unroll
        for (int bq = 0; bq < 2; ++bq) acc[a][bq] = (f32x4){0.f, 0.f, 0.f, 0.f};

    const char* Ab = (const char*)As;
    const char* Bb = (const char*)Bs;

    #pragma unroll
    for (int ks = 0; ks < 8; ++ks) {     // barrier-free: compiler schedules freely
        bf16x8 af[4], bfr[2];
        #pragma unroll
        for (int fr = 0; fr < 4; ++fr) {
            int row = wr * 64 + fr * 16 + lr;
            int col = (ks * 64 + g * 16) ^ ((row & 7) << 4);
            af[fr] = *(const bf16x8*)(Ab + row * 512 + col);
        }
        #pragma unroll
        for (int fc = 0; fc < 2; ++fc) {
            int code = wc * 32 + fc * 16 + lr;
            int col  = (ks * 64 + g * 16) ^ ((code & 7) << 4);
            bfr[fc] = *(const bf16x8*)(Bb + code * 512 + col);
        }
        #pragma unroll
        for (int fr = 0; fr < 4; ++fr)
            #pragma unroll
            for (int fc = 0; fc < 2; ++fc)
                acc[fr][fc] = __builtin_amdgcn_mfma_f32_16x16x32_bf16(
                    af[fr], bfr[fc], acc[fr][fc], 0, 0, 0);
    }

    // ---- epilogue: per-row top2 over this block's 128 codes ----
    __syncthreads();                     // all waves done with As/Bs
    uint4* ldsM = (uint4*)As;            // [8 waves][64 rows]

    float e2v[2];
    #pragma unroll
    for (int fc = 0; fc < 2; ++fc) e2v[fc] = e2[c0 + wc * 32 + fc * 16 + lr];

    #pragma unroll
    for (int fr = 0; fr < 4; ++fr) {
        #pragma unroll
        for (int reg = 0; reg < 4; ++reg) {
            float v0 = __builtin_inff(), v1 = __builtin_inff();
            int   i0 = -1, i1 = -1;
            #pragma unroll
            for (int fc = 0; fc < 2; ++fc) {
                float sv = __builtin_fmaf(-2.f, acc[fr][fc][reg], e2v[fc]);
                top2_insert(v0, i0, v1, i1, sv, c0 + wc * 32 + fc * 16 + lr);
            }
            #pragma unroll
            for (int m = 1; m < 16; m <<= 1) {
                float b0 = __shfl_xor(v0, m), b1 = __shfl_xor(v1, m);
                int  bi0 = __shfl_xor(i0, m), bi1 = __shfl_xor(i1, m);
                top2_merge(v0, i0, v1, i1, b0, bi0, b1, bi1);
            }
            if (lr == 0)
                ldsM[(wr * 4 + wc) * 64 + fr * 16 + g * 4 + reg] =
                    make_uint4(__float_as_uint(v0), (unsigned)i0,
                               __float_as_uint(v1), (unsigned)i1);
        }
    }
    __syncthreads();
    if (t < 128) {
        int wrh = t >> 6, rl = t & 63;
        uint4 E = ldsM[(wrh * 4 + 0) * 64 + rl];
        float v0 = __uint_as_float(E.x), v1 = __uint_as_float(E.z);
        int   i0 = (int)E.y,             i1 = (int)E.w;
        #pragma unroll
        for (int w2 = 1; w2 < 4; ++w2) {
            uint4 F = ldsM[(wrh * 4 + w2) * 64 + rl];
            top2_merge(v0, i0, v1, i1, __uint_as_float(F.x), (int)F.y,
                       __uint_as_float(F.z), (int)F.w);
        }
        scratch[(size_t)(r0 + wrh * 64 + rl) * 64 + chunk] =
            make_uint4(__float_as_uint(v0), (unsigned)i0,
                       __float_as_uint(v1), (unsigned)i1);
    }
}

// ---------------------------------------------------------------------------
// K2 fused: band capture + exact fp32 rescore. One wave per row (4 rows/block).
// Rescore chain bit-identical to the round-1-validated version.
// ---------------------------------------------------------------------------
__global__ __launch_bounds__(256) void band_rescore_kernel(
    const uint4* __restrict__ scratch, const float* __restrict__ x,
    const float* __restrict__ ebT32, const float* __restrict__ e2,
    unsigned* __restrict__ best_idx)
{
    __shared__ unsigned cand[4][16];
    const int w    = threadIdx.x >> 6;
    const int lane = threadIdx.x & 63;
    const int row  = blockIdx.x * 4 + w;

    uint4 e = scratch[(size_t)row * 64 + lane];
    float v0 = __uint_as_float(e.x), v1 = __uint_as_float(e.z);
    float m = v0;
    #pragma unroll
    for (int s = 1; s < 64; s <<= 1) m = fminf(m, __shfl_xor(m, s));
    const float thr = m + 1.0f;
    bool f0 = v0 <= thr, f1 = v1 <= thr;
    unsigned long long b0 = __ballot(f0);
    unsigned long long b1 = __ballot(f1);
    int c0n = __popcll(b0);
    int p0  = __popcll(b0 & ((1ull << lane) - 1));
    int p1  = c0n + __popcll(b1 & ((1ull << lane) - 1));
    if (f0 && p0 < 16) cand[w][p0] = e.y;
    if (f1 && p1 < 16) cand[w][p1] = e.w;
    int cnt = min(c0n + __popcll(b1), 16);

    float d = __builtin_inff();
    unsigned idx = 0xFFFFFFFFu;
    if (lane < cnt) {                    // lanes 0..cnt-1 (cnt<=16)
        idx = cand[w][lane];
        const float* xr = x + (size_t)row * DIM;
        const float* er = ebT32 + (size_t)idx * DIM;
        float f2 = 0.f, dot = 0.f;
        for (int k = 0; k < DIM; ++k) {
            float xv = xr[k];
            f2  = __fadd_rn(f2, __fmul_rn(xv, xv));
            dot = __builtin_fmaf(xv, er[k], dot);
        }
        d = __fadd_rn(__builtin_fmaf(-2.f, dot, f2), e2[idx]);
    }
    #pragma unroll
    for (int mm = 1; mm < 16; mm <<= 1) {
        float    od = __shfl_xor(d, mm);
        unsigned oi = (unsigned)__shfl_xor((int)idx, mm);
        if (od < d || (od == d && oi < idx)) { d = od; idx = oi; }
    }
    if (lane == 0) best_idx[row] = idx;
}

// ---------------------------------------------------------------------------
// K3: gather + straight-through + diff + ind (verbatim from round 2)
// ---------------------------------------------------------------------------
__global__ __launch_bounds__(256) void output_kernel(
    const float* __restrict__ x, const float* __restrict__ ebT32,
    const unsigned* __restrict__ best_idx,
    float* __restrict__ quant, float* __restrict__ diff, float* __restrict__ ind)
{
    const int row = blockIdx.x;
    const int d   = threadIdx.x;
    const unsigned idx = best_idx[row];

    float xv = x[(size_t)row * DIM + d];
    float q  = ebT32[(size_t)idx * DIM + d];
    float dq = __fsub_rn(q, xv);
    quant[(size_t)row * DIM + d] = __fadd_rn(xv, dq);

    float c = __fmul_rn(dq, dq);
    #pragma unroll
    for (int off = 32; off >= 1; off >>= 1) c += __shfl_down(c, off);

    __shared__ float partial[4];
    if ((d & 63) == 0) partial[d >> 6] = c;
    __syncthreads();
    if (d == 0) {
        float s = (partial[0] + partial[1]) + (partial[2] + partial[3]);
        atomicAdd(diff, s * (1.25f / 4194304.f));
        ind[row] = (float)idx;
    }
}

// ---------------------------------------------------------------------------
extern "C" void kernel_launch(void* const* d_in, const int* in_sizes, int n_in,
                              void* d_out, int out_size, void* d_ws, size_t ws_size,
                              hipStream_t stream)
{
    const float* x     = (const float*)d_in[0];   // [16384,256]
    const float* embed = (const float*)d_in[1];   // [256,8192]

    float* out   = (float*)d_out;
    float* quant = out;
    float* diff  = out + 4194304;
    float* ind   = out + 4194305;

    // workspace layout (~21.1 MB)
    char* w = (char*)d_ws;
    ushort*   xb      = (ushort*)(w);                     //  8 MB
    ushort*   eb16    = (ushort*)(w + 8388608);           //  4 MB
    float*    ebT32   = (float*) (w + 12582912);          //  8 MB
    float*    e2      = (float*) (w + 20971520);          // 32 KB
    unsigned* bestidx = (unsigned*)(w + 21004288);        // 64 KB

    // top2 scratch overlays the quantize region (16 MB), freed by K3.
    uint4* scratch = (uint4*)quant;

    prep_kernel<<<2592, 256, 0, stream>>>(x, embed, xb, eb16, ebT32, e2);
    gemm_top2_kernel<<<dim3(64, 128), 512, 0, stream>>>(xb, eb16, e2, scratch);
    band_rescore_kernel<<<4096, 256, 0, stream>>>(scratch, x, ebT32, e2, bestidx);
    hipMemsetAsync(diff, 0, sizeof(float), stream);
    output_kernel<<<NROWS, 256, 0, stream>>>(x, ebT32, bestidx, quant, diff, ind);
}

// Round 4
// 648.479 us; speedup vs baseline: 1.3292x; 1.3292x over previous
//
#include <hip/hip_runtime.h>

static constexpr int DIM   = 256;
static constexpr int NCODE = 8192;
static constexpr int NROWS = 16384;

typedef __bf16 bf16x8 __attribute__((ext_vector_type(8)));
typedef float  f32x4  __attribute__((ext_vector_type(4)));

// ---------------------------------------------------------------------------
// top2 helpers (validated rounds 1-3)
// ---------------------------------------------------------------------------
__device__ __forceinline__ void top2_insert(float& v0, int& i0, float& v1, int& i1,
                                            float s, int si) {
    if (s < v0) { v1 = v0; i1 = i0; v0 = s; i0 = si; }
    else if (s < v1) { v1 = s; i1 = si; }
}
__device__ __forceinline__ void top2_merge(float& v0, int& i0, float& v1, int& i1,
                                           float b0, int bi0, float b1, int bi1) {
    if (b0 < v0) {
        if (b1 < v0) { v0 = b0; i0 = bi0; v1 = b1; i1 = bi1; }
        else         { v1 = v0; i1 = i0;  v0 = b0; i0 = bi0; }
    } else if (b0 < v1) { v1 = b0; i1 = bi0; }
}

// ---------------------------------------------------------------------------
// P0 fused prep: [0,2048) cvt_x | [2048,2560) cvt_e | [2560,2592) e2 (exact)
// ---------------------------------------------------------------------------
__global__ __launch_bounds__(256) void prep_kernel(
    const float* __restrict__ x, const float* __restrict__ embed,
    ushort* __restrict__ xb, ushort* __restrict__ eb16,
    float* __restrict__ ebT32, float* __restrict__ e2)
{
    __shared__ float tile[64][65];
    const int b = blockIdx.x;
    const int t = threadIdx.x;

    if (b < 2048) {                      // ---- cvt_x ----
        int i = b * 256 + t;
        const float4* xp = (const float4*)x + (size_t)i * 2;
        float4 a = xp[0], v = xp[1];
        bf16x8 o;
        o[0] = (__bf16)a.x; o[1] = (__bf16)a.y; o[2] = (__bf16)a.z; o[3] = (__bf16)a.w;
        o[4] = (__bf16)v.x; o[5] = (__bf16)v.y; o[6] = (__bf16)v.z; o[7] = (__bf16)v.w;
        ((bf16x8*)xb)[i] = o;
    } else if (b < 2560) {               // ---- cvt_e ----
        const int eb = b - 2048;
        const int c00 = (eb & 127) * 64;
        const int k0  = (eb >> 7) * 64;
        const int tc  = t & 63, tr4 = t >> 6;
        #pragma unroll
        for (int i = 0; i < 16; ++i) {
            int r = i * 4 + tr4;
            tile[r][tc] = embed[(size_t)(k0 + r) * NCODE + c00 + tc];
        }
        __syncthreads();
        const int cl = t >> 2;
        const int kq = t & 3;
        float vals[16];
        #pragma unroll
        for (int j = 0; j < 16; ++j) vals[j] = tile[kq * 16 + j][cl];
        float* d32 = ebT32 + (size_t)(c00 + cl) * DIM + k0 + kq * 16;
        #pragma unroll
        for (int j = 0; j < 4; ++j)
            *(float4*)(d32 + j * 4) = make_float4(vals[j*4], vals[j*4+1],
                                                  vals[j*4+2], vals[j*4+3]);
        bf16x8 h0, h1;
        #pragma unroll
        for (int j = 0; j < 8; ++j) { h0[j] = (__bf16)vals[j]; h1[j] = (__bf16)vals[8 + j]; }
        ushort* d16 = eb16 + (size_t)(c00 + cl) * DIM + k0 + kq * 16;
        *(bf16x8*)d16 = h0;
        *(bf16x8*)(d16 + 8) = h1;
    } else {                             // ---- e2 (exact serial chain) ----
        int j = (b - 2560) * 256 + t;
        float s = 0.f;
        for (int k = 0; k < DIM; ++k) {
            float v = embed[(size_t)k * NCODE + j];
            s = __fadd_rn(s, __fmul_rn(v, v));
        }
        e2[j] = s;
    }
}

// ---------------------------------------------------------------------------
// K1: B-stationary persistent GEMM + per-row top2 per 128-code chunk.
// Grid = 256 blocks (64 chunks x 4 rowgroups) = 1 block/CU, zero generations.
// B tile [128 codes][K=256] resident (64 KB); A streamed as 64-row tiles
// (32 KB, dbuf). ALL global loads linear; XOR swizzle (row&7)<<4 applied on
// BOTH ds_write and ds_read (reg-staged), so reads are bank-conflict-free.
// 8 waves as 2(row) x 4(code); wave tile 32 rows x 32 codes; 16x16x32 MFMA
// with the round-2-validated fragment/acc mapping.
// Output: compact 8B scratch [chunk][row]: {v0 f32, i0|i1<<13|dq<<26}.
// ---------------------------------------------------------------------------
__global__ __launch_bounds__(512, 1) void gemm_top2_kernel(
    const ushort* __restrict__ xb,   // [NROWS][256] bf16
    const ushort* __restrict__ eb,   // [NCODE][256] bf16 (embed^T)
    const float* __restrict__ e2g,   // [NCODE]
    uint2* __restrict__ scratch)     // [64 chunks][16384 rows]
{
    __shared__ ushort Bs[32768];       // [128][256] swizzled (64 KB)
    __shared__ ushort As[2][16384];    // [64][256] swizzled (2 x 32 KB)
    __shared__ uint4  ldsM[4][64];     // cross-wave top2 merge (4 KB)

    const int t     = threadIdx.x;
    const int chunk = blockIdx.x >> 2;
    const int rg    = blockIdx.x & 3;
    const int c0    = chunk * 128;
    const int rowbase = rg * 4096;

    const int wid = t >> 6, lane = t & 63;
    const int wr  = wid >> 2, wc = wid & 3;    // 2 x 4 wave grid
    const int lr  = lane & 15, g = lane >> 4;

    // ---- prologue: stage B (once) + A tile 0; linear loads, swizzled writes
    {
        const char* bb = (const char*)(eb + (size_t)c0 * DIM);
        uint4 breg[8];
        #pragma unroll
        for (int i = 0; i < 8; ++i)
            breg[i] = *(const uint4*)(bb + i * 8192 + t * 16);
        #pragma unroll
        for (int i = 0; i < 8; ++i) {
            int o = i * 8192 + t * 16;
            int row = o >> 9, col = o & 511;
            *(uint4*)((char*)Bs + row * 512 + (col ^ ((row & 7) << 4))) = breg[i];
        }
        const char* ab = (const char*)(xb + (size_t)rowbase * DIM);
        uint4 areg[4];
        #pragma unroll
        for (int i = 0; i < 4; ++i)
            areg[i] = *(const uint4*)(ab + i * 8192 + t * 16);
        #pragma unroll
        for (int i = 0; i < 4; ++i) {
            int o = i * 8192 + t * 16;
            int row = o >> 9, col = o & 511;
            *(uint4*)((char*)As[0] + row * 512 + (col ^ ((row & 7) << 4))) = areg[i];
        }
    }
    __syncthreads();

    float e2v[2];
    #pragma unroll
    for (int fc = 0; fc < 2; ++fc) e2v[fc] = e2g[c0 + wc * 32 + fc * 16 + lr];

    int cur = 0;
    for (int tt = 0; tt < 64; ++tt) {
        // issue next A-tile loads early (linear, coalesced; ~1 tile of latency cover)
        uint4 areg[4];
        if (tt < 63) {
            const char* ab = (const char*)(xb + (size_t)(rowbase + (tt + 1) * 64) * DIM);
            #pragma unroll
            for (int i = 0; i < 4; ++i)
                areg[i] = *(const uint4*)(ab + i * 8192 + t * 16);
        }

        // ---- compute: barrier-free 32 MFMA / wave ----
        f32x4 acc[2][2];
        #pragma unroll
        for (int a = 0; a < 2; ++a)
            #pragma unroll
            for (int b2 = 0; b2 < 2; ++b2) acc[a][b2] = (f32x4){0.f, 0.f, 0.f, 0.f};

        const char* Ab = (const char*)As[cur];
        const char* Bb = (const char*)Bs;
        #pragma unroll
        for (int ks = 0; ks < 8; ++ks) {
            bf16x8 af[2], bfr[2];
            #pragma unroll
            for (int fr = 0; fr < 2; ++fr) {
                int row = wr * 32 + fr * 16 + lr;
                int col = (ks * 64 + g * 16) ^ ((row & 7) << 4);
                af[fr] = *(const bf16x8*)(Ab + row * 512 + col);
            }
            #pragma unroll
            for (int fc = 0; fc < 2; ++fc) {
                int code = wc * 32 + fc * 16 + lr;
                int col  = (ks * 64 + g * 16) ^ ((code & 7) << 4);
                bfr[fc] = *(const bf16x8*)(Bb + code * 512 + col);
            }
            #pragma unroll
            for (int fr = 0; fr < 2; ++fr)
                #pragma unroll
                for (int fc = 0; fc < 2; ++fc)
                    acc[fr][fc] = __builtin_amdgcn_mfma_f32_16x16x32_bf16(
                        af[fr], bfr[fc], acc[fr][fc], 0, 0, 0);
        }

        // ---- epilogue: per-lane top2 (8 states: fr x reg), shuffle over lr
        #pragma unroll
        for (int fr = 0; fr < 2; ++fr) {
            #pragma unroll
            for (int reg = 0; reg < 4; ++reg) {
                float v0 = __builtin_inff(), v1 = __builtin_inff();
                int   i0 = -1, i1 = -1;
                #pragma unroll
                for (int fc = 0; fc < 2; ++fc) {
                    float sv = __builtin_fmaf(-2.f, acc[fr][fc][reg], e2v[fc]);
                    top2_insert(v0, i0, v1, i1, sv, c0 + wc * 32 + fc * 16 + lr);
                }
                #pragma unroll
                for (int m = 1; m < 16; m <<= 1) {
                    float b0 = __shfl_xor(v0, m), b1 = __shfl_xor(v1, m);
                    int  bi0 = __shfl_xor(i0, m), bi1 = __shfl_xor(i1, m);
                    top2_merge(v0, i0, v1, i1, b0, bi0, b1, bi1);
                }
                if (lr == 0)
                    ldsM[wc][wr * 32 + fr * 16 + g * 4 + reg] =
                        make_uint4(__float_as_uint(v0), (unsigned)i0,
                                   __float_as_uint(v1), (unsigned)i1);
            }
        }
        __syncthreads();                 // ldsM ready; As[cur] reads all done

        if (t < 64) {                    // merge 4 code-waves -> compact 8B entry
            uint4 E = ldsM[0][t];
            float v0 = __uint_as_float(E.x), v1 = __uint_as_float(E.z);
            int   i0 = (int)E.y,             i1 = (int)E.w;
            #pragma unroll
            for (int k = 1; k < 4; ++k) {
                uint4 F = ldsM[k][t];
                top2_merge(v0, i0, v1, i1, __uint_as_float(F.x), (int)F.y,
                           __uint_as_float(F.z), (int)F.w);
            }
            float delta = v1 - v0;
            unsigned dq = (unsigned)min(63, (int)(delta * 32.f));  // round DOWN
            unsigned w2 = (unsigned)i0 | ((unsigned)i1 << 13) | (dq << 26);
            scratch[(size_t)chunk * NROWS + rowbase + tt * 64 + t] =
                make_uint2(__float_as_uint(v0), w2);
        }

        if (tt < 63) {                   // publish next A tile (swizzled writes)
            #pragma unroll
            for (int i = 0; i < 4; ++i) {
                int o = i * 8192 + t * 16;
                int row = o >> 9, col = o & 511;
                *(uint4*)((char*)As[cur ^ 1] + row * 512 + (col ^ ((row & 7) << 4))) = areg[i];
            }
        }
        __syncthreads();                 // As[next] ready; ldsM reusable
        cur ^= 1;
    }
}

// ---------------------------------------------------------------------------
// K2 fused finalize: band capture + exact fp32 rescore + gather/diff/ind.
// 256 blocks x 64 rows. Coalesced [chunk][row] scratch reads (512B/wave).
// Rescore chain bit-identical to the round-1-validated version.
// ---------------------------------------------------------------------------
__global__ __launch_bounds__(256) void finalize_kernel(
    const uint2* __restrict__ scratch, const float* __restrict__ x,
    const float* __restrict__ ebT32, const float* __restrict__ e2g,
    float* __restrict__ quant, float* __restrict__ diff, float* __restrict__ ind)
{
    __shared__ float    wmin[4][64];
    __shared__ float    thr[64];
    __shared__ unsigned cnt[64];
    __shared__ unsigned cand[64][12];
    __shared__ unsigned bestIdx[64];
    __shared__ float    partial[4];

    const int t  = threadIdx.x;
    const int w  = t >> 6, l = t & 63;
    const int R0 = blockIdx.x * 64;

    if (t < 64) cnt[t] = 0;

    // pass A: per-row global approx min over 64 chunks (16 per wave)
    float m = __builtin_inff();
    #pragma unroll 4
    for (int i = 0; i < 16; ++i) {
        uint2 e = scratch[(size_t)(w * 16 + i) * NROWS + R0 + l];
        m = fminf(m, __uint_as_float(e.x));
    }
    wmin[w][l] = m;
    __syncthreads();
    if (t < 64)
        thr[t] = fminf(fminf(wmin[0][t], wmin[1][t]),
                       fminf(wmin[2][t], wmin[3][t])) + 1.0f;
    __syncthreads();

    // pass B: collect in-band candidates (v1 reconstructed from below -> never misses)
    const float th = thr[l];
    for (int i = 0; i < 16; ++i) {
        uint2 e = scratch[(size_t)(w * 16 + i) * NROWS + R0 + l];
        float v0 = __uint_as_float(e.x);
        if (v0 <= th) {
            unsigned s = atomicAdd(&cnt[l], 1u);
            if (s < 12) cand[l][s] = e.y & 8191u;
        }
        float v1lo = v0 + (float)((e.y >> 26) & 63u) * 0.03125f;
        if (v1lo <= th) {
            unsigned s = atomicAdd(&cnt[l], 1u);
            if (s < 12) cand[l][s] = (e.y >> 13) & 8191u;
        }
    }
    __syncthreads();

    // rescore: lane = rl*4 + slot; all candidate chains run concurrently
    const int rl = l >> 2, slot = l & 3;
    const int rrow = R0 + w * 16 + rl;
    const int cn = min((int)cnt[w * 16 + rl], 12);
    float best = __builtin_inff();
    unsigned bidx = 0xFFFFFFFFu;
    for (int s = slot; s < cn; s += 4) {
        unsigned idx = cand[w * 16 + rl][s];
        const float* xr = x + (size_t)rrow * DIM;
        const float* er = ebT32 + (size_t)idx * DIM;
        float f2 = 0.f, dot = 0.f;
        for (int k = 0; k < DIM; ++k) {
            float xv = xr[k];
            f2  = __fadd_rn(f2, __fmul_rn(xv, xv));
            dot = __builtin_fmaf(xv, er[k], dot);
        }
        float d = __fadd_rn(__builtin_fmaf(-2.f, dot, f2), e2g[idx]);
        if (d < best || (d == best && idx < bidx)) { best = d; bidx = idx; }
    }
    #pragma unroll
    for (int mm = 1; mm < 4; mm <<= 1) {
        float    od = __shfl_xor(best, mm);
        unsigned oi = (unsigned)__shfl_xor((int)bidx, mm);
        if (od < best || (od == best && oi < bidx)) { best = od; bidx = oi; }
    }
    if (slot == 0) bestIdx[w * 16 + rl] = bidx;
    __syncthreads();

    // output: gather + straight-through + diff accumulation
    float accv = 0.f;
    for (int r = 0; r < 64; ++r) {
        const int row2 = R0 + r;
        const unsigned idx = bestIdx[r];
        float xv = x[(size_t)row2 * DIM + t];
        float q  = ebT32[(size_t)idx * DIM + t];
        float dq = __fsub_rn(q, xv);
        quant[(size_t)row2 * DIM + t] = __fadd_rn(xv, dq);
        accv += __fmul_rn(dq, dq);
    }
    #pragma unroll
    for (int off = 32; off >= 1; off >>= 1) accv += __shfl_down(accv, off);
    if (l == 0) partial[w] = accv;
    __syncthreads();
    if (t == 0) {
        float s = (partial[0] + partial[1]) + (partial[2] + partial[3]);
        atomicAdd(diff, s * (1.25f / 4194304.f));
    }
    if (t < 64) ind[R0 + t] = (float)bestIdx[t];
}

// ---------------------------------------------------------------------------
extern "C" void kernel_launch(void* const* d_in, const int* in_sizes, int n_in,
                              void* d_out, int out_size, void* d_ws, size_t ws_size,
                              hipStream_t stream)
{
    const float* x     = (const float*)d_in[0];   // [16384,256]
    const float* embed = (const float*)d_in[1];   // [256,8192]

    float* out   = (float*)d_out;
    float* quant = out;
    float* diff  = out + 4194304;
    float* ind   = out + 4194305;

    // xb (bf16 x, 8 MB) overlays the quantize region: written by prep, read
    // only by gemm, overwritten by finalize (stream-ordered) -> safe.
    ushort* xb = (ushort*)quant;

    // workspace (20.1 MB, under the 22.1 MB proven-available)
    char* w = (char*)d_ws;
    ushort* eb16    = (ushort*)(w);               //  4 MB
    float*  ebT32   = (float*) (w + 4194304);     //  8 MB
    float*  e2      = (float*) (w + 12582912);    // 32 KB
    uint2*  scratch = (uint2*) (w + 12615680);    //  8 MB  [64][16384]

    prep_kernel<<<2592, 256, 0, stream>>>(x, embed, xb, eb16, ebT32, e2);
    gemm_top2_kernel<<<256, 512, 0, stream>>>(xb, eb16, e2, scratch);
    hipMemsetAsync(diff, 0, sizeof(float), stream);
    finalize_kernel<<<256, 256, 0, stream>>>(scratch, x, ebT32, e2, quant, diff, ind);
}